// Round 5
// baseline (299.240 us; speedup 1.0000x reference)
//
#include <hip/hip_runtime.h>
#include <cstdint>
#include <cstddef>

typedef unsigned short u16;
typedef __attribute__((ext_vector_type(8))) short bf16x8;
typedef __attribute__((ext_vector_type(4))) float f32x4;

__device__ inline float bf2f(u16 u) { return __uint_as_float(((unsigned)u) << 16); }
__device__ inline u16 f2bf(float f) {
  unsigned u = __float_as_uint(f);
  u += 0x7fffu + ((u >> 16) & 1u);   // RNE
  return (u16)(u >> 16);
}

__device__ inline void async16(const u16* g, u16* l) {
  __builtin_amdgcn_global_load_lds(
      (const __attribute__((address_space(1))) void*)g,
      (__attribute__((address_space(3))) void*)l, 16, 0, 0);
}

__device__ inline void unpack8(uint4 q, float* o) {
  o[0] = bf2f((u16)(q.x & 0xffffu)); o[1] = bf2f((u16)(q.x >> 16));
  o[2] = bf2f((u16)(q.y & 0xffffu)); o[3] = bf2f((u16)(q.y >> 16));
  o[4] = bf2f((u16)(q.z & 0xffffu)); o[5] = bf2f((u16)(q.z >> 16));
  o[6] = bf2f((u16)(q.w & 0xffffu)); o[7] = bf2f((u16)(q.w >> 16));
}

__device__ inline uint4 pack8(const float* v) {
  uint4 q;
  q.x = (unsigned)f2bf(v[0]) | ((unsigned)f2bf(v[1]) << 16);
  q.y = (unsigned)f2bf(v[2]) | ((unsigned)f2bf(v[3]) << 16);
  q.z = (unsigned)f2bf(v[4]) | ((unsigned)f2bf(v[5]) << 16);
  q.w = (unsigned)f2bf(v[6]) | ((unsigned)f2bf(v[7]) << 16);
  return q;
}

__device__ inline float fast_sigmoid(float z) {
  return 1.0f / (1.0f + exp2f(-1.4426950408889634f * z));
}
__device__ inline float fast_tanh(float z) {
  return 1.0f - 2.0f / (1.0f + exp2f(2.8853900817779268f * z));
}

// ---------------- fused fp32 -> bf16 convert ----------------
struct ConvAll { const float* src[8]; u16* dst[8]; };

__global__ __launch_bounds__(256) void convert_all(ConvAll a) {
  const int b = blockIdx.x;
  int which, off;
  if (b < 8192)        { which = 0; off = b; }
  else if (b < 16384)  { which = 1; off = b - 8192; }
  else { const int t = b - 16384; which = 2 + (t >> 10); off = t & 1023; }
  const float* __restrict__ s = a.src[which];
  u16* __restrict__ d = a.dst[which];
  const int i = (off * 256 + threadIdx.x) * 4;
  float4 v = *(const float4*)(s + i);
  uint2 o;
  o.x = (unsigned)f2bf(v.x) | ((unsigned)f2bf(v.y) << 16);
  o.y = (unsigned)f2bf(v.z) | ((unsigned)f2bf(v.w) << 16);
  *(uint2*)(d + i) = o;
}

// ---------------- batched NT GEMM: 128x128 tile, BK=64, XOR-swizzled LDS ----------------
// NG = 2^NG_LOG2 gates. Per XCD: pr selects A row-tile group, cc = (gate, col);
// gates sharing an A input must be adjacent in the gate table so the A-tile is
// fetched once per XCD and served from L2 for all its column-blocks.
struct Gemm4 { const u16* A[4]; const u16* Bw[4]; u16* Y[4]; };

template <int NG_LOG2>
__global__ __launch_bounds__(256) void gemm_batch(Gemm4 args) {
  const int p = blockIdx.x;
  const int xcd = p & 7;
  const int s = p >> 3;
  const int pr = s >> (3 + NG_LOG2);
  const int cc = s & ((8 << NG_LOG2) - 1);
  const int gate = cc >> 3;
  const int col  = cc & 7;
  const int r = pr * 8 + xcd;

  const u16* __restrict__ A  = args.A[gate];
  const u16* __restrict__ Bw = args.Bw[gate];
  u16* __restrict__ Y = args.Y[gate];

  __shared__ __attribute__((aligned(16))) u16 As[128 * 64];  // 16 KiB
  __shared__ __attribute__((aligned(16))) u16 Bs[128 * 64];  // 16 KiB

  const int tid  = threadIdx.x;
  const int lane = tid & 63;
  const int w    = tid >> 6;
  const int wm   = w >> 1;
  const int wn   = w & 1;

  const int rowBlk = r * 128;
  const int colBlk = col * 128;

  // staging: lane l -> row chunk+(l>>3), global k-group ((l&7)^(l>>3))*8 (XOR swizzle)
  const int srow = lane >> 3;
  const int scol = ((lane & 7) ^ srow) * 8;
  const u16* gA[4]; const u16* gB[4]; u16* lA[4]; u16* lB[4];
#pragma unroll
  for (int i = 0; i < 4; i++) {
    const int rr = w * 32 + i * 8;
    gA[i] = A  + (size_t)(rowBlk + rr + srow) * 1024 + scol;
    gB[i] = Bw + (size_t)(colBlk + rr + srow) * 1024 + scol;
    lA[i] = &As[rr * 64];
    lB[i] = &Bs[rr * 64];
  }

  const int swz = (((lane >> 4) ^ (lane & 7)) << 3);
  const int fa = (wm * 64 + (lane & 15)) * 64 + swz;
  const int fb = (wn * 64 + (lane & 15)) * 64 + swz;

  f32x4 acc[4][4] = {};

  for (int k0 = 0; k0 < 1024; k0 += 64) {
#pragma unroll
    for (int i = 0; i < 4; i++) {
      async16(gA[i] + k0, lA[i]);
      async16(gB[i] + k0, lB[i]);
    }
    __syncthreads();
#pragma unroll
    for (int kk = 0; kk < 2; kk++) {
      const int kx = kk << 5;
      bf16x8 af[4], bfr[4];
#pragma unroll
      for (int t = 0; t < 4; t++) {
        af[t]  = *(const bf16x8*)&As[(fa + t * 1024) ^ kx];
        bfr[t] = *(const bf16x8*)&Bs[(fb + t * 1024) ^ kx];
      }
#pragma unroll
      for (int tm = 0; tm < 4; tm++)
#pragma unroll
        for (int tn = 0; tn < 4; tn++)
          acc[tm][tn] = __builtin_amdgcn_mfma_f32_16x16x32_bf16(af[tm], bfr[tn], acc[tm][tn], 0, 0, 0);
    }
    __syncthreads();
  }

  const int rBase = rowBlk + wm * 64 + (lane >> 4) * 4;
  const int cBase = colBlk + wn * 64 + (lane & 15);
#pragma unroll
  for (int tm = 0; tm < 4; tm++) {
#pragma unroll
    for (int i = 0; i < 4; i++) {
      const size_t rr = (size_t)(rBase + tm * 16 + i);
#pragma unroll
      for (int tn = 0; tn < 4; tn++)
        Y[rr * 1024 + cBase + tn * 16] = f2bf(acc[tm][tn][i]);
    }
  }
}

// ---------------- r gate: wave-per-row, no barriers ----------------
__global__ __launch_bounds__(256) void rgate_kernel(
    const u16* __restrict__ Yrh, const u16* __restrict__ Yrx,
    const u16* __restrict__ hb, const float* __restrict__ gamma,
    const float* __restrict__ beta, u16* __restrict__ hrb) {
  const int row  = blockIdx.x * 4 + (threadIdx.x >> 6);
  const int lane = threadIdx.x & 63;
  const size_t rb = (size_t)row * 1024;

  uint4 qa[2], qb[2], qh[2];
  qa[0] = *(const uint4*)(Yrh + rb + lane * 8);
  qa[1] = *(const uint4*)(Yrh + rb + 512 + lane * 8);
  qb[0] = *(const uint4*)(Yrx + rb + lane * 8);
  qb[1] = *(const uint4*)(Yrx + rb + 512 + lane * 8);
  qh[0] = *(const uint4*)(hb  + rb + lane * 8);
  qh[1] = *(const uint4*)(hb  + rb + 512 + lane * 8);

  float s0 = 0.f, s0q = 0.f, s1 = 0.f, s1q = 0.f;
  float tmp[8];
#pragma unroll
  for (int c = 0; c < 2; c++) {
    unpack8(qa[c], tmp);
#pragma unroll
    for (int j = 0; j < 8; j++) { s0 += tmp[j]; s0q += tmp[j] * tmp[j]; }
    unpack8(qb[c], tmp);
#pragma unroll
    for (int j = 0; j < 8; j++) { s1 += tmp[j]; s1q += tmp[j] * tmp[j]; }
  }
#pragma unroll
  for (int off = 1; off < 64; off <<= 1) {
    s0 += __shfl_xor(s0, off, 64);  s0q += __shfl_xor(s0q, off, 64);
    s1 += __shfl_xor(s1, off, 64);  s1q += __shfl_xor(s1q, off, 64);
  }

  const float inv = 1.0f / 1024.0f;
  const float mu0 = s0 * inv, rs0 = rsqrtf(s0q * inv - mu0 * mu0 + 1e-5f);
  const float mu1 = s1 * inv, rs1 = rsqrtf(s1q * inv - mu1 * mu1 + 1e-5f);

#pragma unroll
  for (int c = 0; c < 2; c++) {
    const int cb = c * 512 + lane * 8;
    float va[8], vb[8], vh[8], o[8];
    unpack8(qa[c], va); unpack8(qb[c], vb); unpack8(qh[c], vh);
#pragma unroll
    for (int j = 0; j < 8; j++) {
      const float ln0 = (va[j] - mu0) * rs0 * gamma[cb + j] + beta[cb + j];
      const float ln1 = (vb[j] - mu1) * rs1 * gamma[1024 + cb + j] + beta[1024 + cb + j];
      const float rg = fast_sigmoid(ln0 + ln1);
      o[j] = vh[j] * rg;
    }
    *(uint4*)(hrb + rb + cb) = pack8(o);  // aliases Yrx: per-thread read-before-write
  }
}

// ---------------- final: wave-per-row, h read in fp32 ----------------
__global__ __launch_bounds__(256) void final_fuse(
    const u16* __restrict__ Yuh, const u16* __restrict__ Yux,
    const u16* __restrict__ Ych, const u16* __restrict__ Ycx,
    const float* __restrict__ h, const float* __restrict__ gamma,
    const float* __restrict__ beta, float* __restrict__ out) {
  const int row  = blockIdx.x * 4 + (threadIdx.x >> 6);
  const int lane = threadIdx.x & 63;
  const size_t rb = (size_t)row * 1024;

  uint4 q0[2], q1[2], q2[2], q3[2];
  float4 hf[4];
#pragma unroll
  for (int c = 0; c < 2; c++) {
    const int cb = c * 512 + lane * 8;
    q0[c] = *(const uint4*)(Yuh + rb + cb);
    q1[c] = *(const uint4*)(Yux + rb + cb);
    q2[c] = *(const uint4*)(Ych + rb + cb);
    q3[c] = *(const uint4*)(Ycx + rb + cb);
    hf[c * 2]     = *(const float4*)(h + rb + cb);
    hf[c * 2 + 1] = *(const float4*)(h + rb + cb + 4);
  }

  float s[8] = {0.f, 0.f, 0.f, 0.f, 0.f, 0.f, 0.f, 0.f};
  float tmp[8];
#pragma unroll
  for (int c = 0; c < 2; c++) {
    unpack8(q0[c], tmp);
#pragma unroll
    for (int j = 0; j < 8; j++) { s[0] += tmp[j]; s[1] += tmp[j] * tmp[j]; }
    unpack8(q1[c], tmp);
#pragma unroll
    for (int j = 0; j < 8; j++) { s[2] += tmp[j]; s[3] += tmp[j] * tmp[j]; }
    unpack8(q2[c], tmp);
#pragma unroll
    for (int j = 0; j < 8; j++) { s[4] += tmp[j]; s[5] += tmp[j] * tmp[j]; }
    unpack8(q3[c], tmp);
#pragma unroll
    for (int j = 0; j < 8; j++) { s[6] += tmp[j]; s[7] += tmp[j] * tmp[j]; }
  }
#pragma unroll
  for (int off = 1; off < 64; off <<= 1) {
#pragma unroll
    for (int q = 0; q < 8; q++) s[q] += __shfl_xor(s[q], off, 64);
  }

  const float inv = 1.0f / 1024.0f;
  const float mu0 = s[0] * inv, rs0 = rsqrtf(s[1] * inv - mu0 * mu0 + 1e-5f);
  const float mu1 = s[2] * inv, rs1 = rsqrtf(s[3] * inv - mu1 * mu1 + 1e-5f);
  const float mu2 = s[4] * inv, rs2 = rsqrtf(s[5] * inv - mu2 * mu2 + 1e-5f);
  const float mu3 = s[6] * inv, rs3 = rsqrtf(s[7] * inv - mu3 * mu3 + 1e-5f);

#pragma unroll
  for (int c = 0; c < 2; c++) {
    const int cb = c * 512 + lane * 8;
    float v0[8], v1[8], v2[8], v3[8];
    unpack8(q0[c], v0); unpack8(q1[c], v1); unpack8(q2[c], v2); unpack8(q3[c], v3);
    const float* hv = (const float*)&hf[c * 2];
    float o[8];
#pragma unroll
    for (int j = 0; j < 8; j++) {
      const int cc = cb + j;
      const float ln2 = (v0[j] - mu0) * rs0 * gamma[2 * 1024 + cc] + beta[2 * 1024 + cc];
      const float ln3 = (v1[j] - mu1) * rs1 * gamma[3 * 1024 + cc] + beta[3 * 1024 + cc];
      const float ln4 = (v2[j] - mu2) * rs2 * gamma[4 * 1024 + cc] + beta[4 * 1024 + cc];
      const float ln5 = (v3[j] - mu3) * rs3 * gamma[5 * 1024 + cc] + beta[5 * 1024 + cc];
      const float u  = fast_sigmoid(ln2 + ln3);
      const float cg = fast_tanh(ln4 + ln5);
      o[j] = (1.0f - u) * hv[j] + u * cg;
    }
    *(float4*)(out + rb + cb)     = *(float4*)&o[0];
    *(float4*)(out + rb + cb + 4) = *(float4*)&o[4];
  }
}

extern "C" void kernel_launch(void* const* d_in, const int* in_sizes, int n_in,
                              void* d_out, int out_size, void* d_ws, size_t ws_size,
                              hipStream_t stream) {
  const float* x  = (const float*)d_in[0];
  const float* h  = (const float*)d_in[1];
  const float* Ws[6] = {(const float*)d_in[2], (const float*)d_in[3],
                        (const float*)d_in[4], (const float*)d_in[5],
                        (const float*)d_in[6], (const float*)d_in[7]};
  const float* gamma = (const float*)d_in[8];
  const float* beta  = (const float*)d_in[9];
  float* out = (float*)d_out;

  char* ws = (char*)d_ws;
  const size_t SZ_ACT = (size_t)8192 * 1024 * 2;  // 16 MiB (bf16)
  const size_t SZ_W   = (size_t)1024 * 1024 * 2;  // 2 MiB

  u16* xb = (u16*)(ws);
  u16* hb = (u16*)(ws + SZ_ACT);
  u16* wb[6];
  for (int i = 0; i < 6; i++) wb[i] = (u16*)(ws + 2 * SZ_ACT + i * SZ_W);
  char* ybase = ws + 2 * SZ_ACT + 6 * SZ_W;
  u16* Y0 = (u16*)(ybase);                 // r_hidden; reused for c_hidden out
  u16* Y1 = (u16*)(ybase + SZ_ACT);        // r_input;  reused for hr
  u16* Y2 = (u16*)(ybase + 2 * SZ_ACT);    // u_hidden
  u16* Y3 = (u16*)(ybase + 3 * SZ_ACT);    // u_input
  u16* Y5 = (u16*)(ybase + 4 * SZ_ACT);    // c_input

  // 1) one fused convert launch
  ConvAll ca = {};
  ca.src[0] = x; ca.dst[0] = xb;
  ca.src[1] = h; ca.dst[1] = hb;
  for (int i = 0; i < 6; i++) { ca.src[2 + i] = Ws[i]; ca.dst[2 + i] = wb[i]; }
  convert_all<<<16384 + 6 * 1024, 256, 0, stream>>>(ca);

  // 2) batch A: r_h = h@W_r^T, r_x = x@U_r^T   (1024 blocks)
  Gemm4 ga = {};
  ga.A[0] = hb; ga.Bw[0] = wb[0]; ga.Y[0] = Y0;
  ga.A[1] = xb; ga.Bw[1] = wb[1]; ga.Y[1] = Y1;
  gemm_batch<1><<<1024, 256, 0, stream>>>(ga);

  // 3) r gate + hr (hr overwrites Y1; per-thread read-before-write)
  rgate_kernel<<<2048, 256, 0, stream>>>(Y0, Y1, hb, gamma, beta, Y1);

  // 4) batch B: u_x, c_x (share xb tile), u_h, c_h  (2048 blocks)
  Gemm4 gb = {};
  gb.A[0] = xb; gb.Bw[0] = wb[3]; gb.Y[0] = Y3;   // u_x = x@U_u^T
  gb.A[1] = xb; gb.Bw[1] = wb[5]; gb.Y[1] = Y5;   // c_x = x@U_c^T
  gb.A[2] = hb; gb.Bw[2] = wb[2]; gb.Y[2] = Y2;   // u_h = h@W_u^T
  gb.A[3] = Y1; gb.Bw[3] = wb[4]; gb.Y[3] = Y0;   // c_h = hr@W_c^T
  gemm_batch<2><<<2048, 256, 0, stream>>>(gb);

  // 5) u, c, out (h in fp32)
  final_fuse<<<2048, 256, 0, stream>>>(Y2, Y3, Y0, Y5, h, gamma, beta, out);
}

// Round 6
// 284.822 us; speedup vs baseline: 1.0506x; 1.0506x over previous
//
#include <hip/hip_runtime.h>
#include <cstdint>
#include <cstddef>

typedef unsigned short u16;
typedef unsigned char u8;
typedef __attribute__((ext_vector_type(8))) short bf16x8;
typedef __attribute__((ext_vector_type(4))) float f32x4;
typedef __attribute__((ext_vector_type(4))) int i32x4;
typedef __attribute__((ext_vector_type(8))) int i32x8;

__device__ inline float bf2f(u16 u) { return __uint_as_float(((unsigned)u) << 16); }
__device__ inline unsigned f2bf(float f) {
  unsigned u = __float_as_uint(f);
  u += 0x7fffu + ((u >> 16) & 1u);   // RNE
  return u >> 16;
}

// f32 -> OCP e4m3fn (RNE). Caller guarantees |f| <= 448.
__device__ inline unsigned f2fp8(float f) {
  unsigned s = (__float_as_uint(f) >> 31) << 7;
  float a = fabsf(f);
  if (a >= 0.015625f) {              // normal range
    unsigned u = __float_as_uint(a);
    u += 0x7FFFFu + ((u >> 20) & 1u);
    unsigned e = (u >> 23) - 120u;   // e32 - 127 + 7
    unsigned m = (u >> 20) & 7u;
    return s | (e << 3) | m;
  }
  int m = (int)rintf(a * 512.0f);    // subnormal step 2^-9 (m=8 rolls to min normal)
  return s | (unsigned)m;
}

__device__ inline void async16(const void* g, void* l) {
  __builtin_amdgcn_global_load_lds(
      (const __attribute__((address_space(1))) void*)g,
      (__attribute__((address_space(3))) void*)l, 16, 0, 0);
}

__device__ inline i32x8 join8(i32x4 lo, i32x4 hi) {
  i32x8 r;
  r[0] = lo[0]; r[1] = lo[1]; r[2] = lo[2]; r[3] = lo[3];
  r[4] = hi[0]; r[5] = hi[1]; r[6] = hi[2]; r[7] = hi[3];
  return r;
}

__device__ inline void unpack8(uint4 q, float* o) {
  o[0] = bf2f((u16)(q.x & 0xffffu)); o[1] = bf2f((u16)(q.x >> 16));
  o[2] = bf2f((u16)(q.y & 0xffffu)); o[3] = bf2f((u16)(q.y >> 16));
  o[4] = bf2f((u16)(q.z & 0xffffu)); o[5] = bf2f((u16)(q.z >> 16));
  o[6] = bf2f((u16)(q.w & 0xffffu)); o[7] = bf2f((u16)(q.w >> 16));
}

__device__ inline uint4 pack8(const float* v) {
  uint4 q;
  q.x = f2bf(v[0]) | (f2bf(v[1]) << 16);
  q.y = f2bf(v[2]) | (f2bf(v[3]) << 16);
  q.z = f2bf(v[4]) | (f2bf(v[5]) << 16);
  q.w = f2bf(v[6]) | (f2bf(v[7]) << 16);
  return q;
}

__device__ inline float fast_sigmoid(float z) {
  return 1.0f / (1.0f + exp2f(-1.4426950408889634f * z));
}
__device__ inline float fast_tanh(float z) {
  return 1.0f - 2.0f / (1.0f + exp2f(2.8853900817779268f * z));
}

// ---------------- fused convert: x,h -> bf16+fp8; W_r,U_r -> fp8(x2^13); W_u,U_u,W_c,U_c -> bf16 ----------------
struct ConvArgs2 {
  const float* x; const float* h; const float* wr; const float* ur;
  const float* wbf[4];               // W_u, U_u, W_c, U_c
  u16* xb; u16* hb; u8* x8; u8* h8; u8* w8r; u8* w8u;
  u16* wbo[4];
};

__global__ __launch_bounds__(256) void convert_all(ConvArgs2 a) {
  const int b = blockIdx.x;
  const int t = threadIdx.x;
  if (b < 16384) {
    const bool isx = b < 8192;
    const int off = isx ? b : b - 8192;
    const float* __restrict__ s = isx ? a.x : a.h;
    u16* __restrict__ db = isx ? a.xb : a.hb;
    u8*  __restrict__ d8 = isx ? a.x8 : a.h8;
    const int i = (off * 256 + t) * 4;
    float4 v = *(const float4*)(s + i);
    uint2 o;
    o.x = f2bf(v.x) | (f2bf(v.y) << 16);
    o.y = f2bf(v.z) | (f2bf(v.w) << 16);
    *(uint2*)(db + i) = o;
    unsigned q = f2fp8(v.x) | (f2fp8(v.y) << 8) | (f2fp8(v.z) << 16) | (f2fp8(v.w) << 24);
    *(unsigned*)(d8 + i) = q;
  } else if (b < 18432) {
    const bool isr = b < 17408;
    const int off = isr ? b - 16384 : b - 17408;
    const float* __restrict__ s = isr ? a.wr : a.ur;
    u8* __restrict__ d8 = isr ? a.w8r : a.w8u;
    const int i = (off * 256 + t) * 4;
    float4 v = *(const float4*)(s + i);
    unsigned q = f2fp8(v.x * 8192.f) | (f2fp8(v.y * 8192.f) << 8) |
                 (f2fp8(v.z * 8192.f) << 16) | (f2fp8(v.w * 8192.f) << 24);
    *(unsigned*)(d8 + i) = q;
  } else {
    const int tt = b - 18432;
    const int which = tt >> 10;
    const int off = tt & 1023;
    const float* __restrict__ s = a.wbf[which];
    u16* __restrict__ d = a.wbo[which];
    const int i = (off * 256 + t) * 4;
    float4 v = *(const float4*)(s + i);
    uint2 o;
    o.x = f2bf(v.x) | (f2bf(v.y) << 16);
    o.y = f2bf(v.z) | (f2bf(v.w) << 16);
    *(uint2*)(d + i) = o;
  }
}

// ---------------- fp8 MX GEMM: Y = A @ W^T, 128x128 tile, BK=128, fixed e8m0 scales ----------------
// A: activations fp8 (scale 1.0 = byte 127); W: fp8 pre-scaled x2^13 (scale 2^-13 = byte 114).
// LDS rows = 128 B = 8 16B groups; XOR swizzle phys = logical ^ (row&7), staged via the
// lane-permuted global column trick (global_load_lds writes base + lane*16).
struct GemmF8 { const u8* A[2]; const u8* Bw[2]; u16* Y[2]; };

__global__ __launch_bounds__(256) void gemm_fp8(GemmF8 args) {
  const int p = blockIdx.x;          // 1024 blocks
  const int xcd = p & 7;
  const int s = p >> 3;              // 0..127
  const int pr = s >> 4;             // 0..7
  const int cc = s & 15;
  const int gate = cc >> 3;          // 0..1
  const int col = cc & 7;
  const int r = pr * 8 + xcd;        // 0..63

  const u8* __restrict__ A  = args.A[gate];
  const u8* __restrict__ Bw = args.Bw[gate];
  u16* __restrict__ Y = args.Y[gate];

  __shared__ __attribute__((aligned(16))) u8 As[128 * 128];  // 16 KiB
  __shared__ __attribute__((aligned(16))) u8 Bs[128 * 128];  // 16 KiB

  const int tid  = threadIdx.x;
  const int lane = tid & 63;
  const int w    = tid >> 6;
  const int wm   = w >> 1;
  const int wn   = w & 1;

  const int rowBlk = r * 128;
  const int colBlk = col * 128;

  // staging: lane l -> row chunk+(l>>3), global byte-col ((l&7)^(l>>3))*16
  const int srow = lane >> 3;
  const int scol = ((lane & 7) ^ srow) * 16;
  const u8* gA[4]; const u8* gB[4]; u8* lA[4]; u8* lB[4];
#pragma unroll
  for (int i = 0; i < 4; i++) {
    const int rr = w * 32 + i * 8;
    gA[i] = A  + (size_t)(rowBlk + rr + srow) * 1024 + scol;
    gB[i] = Bw + (size_t)(colBlk + rr + srow) * 1024 + scol;
    lA[i] = &As[rr * 128];
    lB[i] = &Bs[rr * 128];
  }

  const int sw = lane & 7;           // == frag row & 7 for every tile
  const int g0 = (lane >> 4) * 2;    // lane's two logical 16B k-groups
  const int o0 = ((g0 ^ sw) << 4);
  const int o1 = (((g0 + 1) ^ sw) << 4);
  const int frA = (wm * 64 + (lane & 15)) * 128;
  const int frB = (wn * 64 + (lane & 15)) * 128;

  f32x4 acc[4][4] = {};

  for (int k0 = 0; k0 < 1024; k0 += 128) {
#pragma unroll
    for (int i = 0; i < 4; i++) {
      async16(gA[i] + k0, lA[i]);
      async16(gB[i] + k0, lB[i]);
    }
    __syncthreads();
    i32x8 af[4], bfr[4];
#pragma unroll
    for (int t = 0; t < 4; t++) {
      const int ra = frA + t * 16 * 128;
      const int rb = frB + t * 16 * 128;
      af[t]  = join8(*(const i32x4*)&As[ra + o0], *(const i32x4*)&As[ra + o1]);
      bfr[t] = join8(*(const i32x4*)&Bs[rb + o0], *(const i32x4*)&Bs[rb + o1]);
    }
#pragma unroll
    for (int tm = 0; tm < 4; tm++)
#pragma unroll
      for (int tn = 0; tn < 4; tn++)
        acc[tm][tn] = __builtin_amdgcn_mfma_scale_f32_16x16x128_f8f6f4(
            af[tm], bfr[tn], acc[tm][tn],
            0, 0,            // cbsz=fp8(e4m3), blgp=fp8(e4m3)
            0, 127,          // opsel_a, scale_a = 2^0
            0, 114);         // opsel_b, scale_b = 2^-13
    __syncthreads();
  }

  const int rBase = rowBlk + wm * 64 + (lane >> 4) * 4;
  const int cBase = colBlk + wn * 64 + (lane & 15);
#pragma unroll
  for (int tm = 0; tm < 4; tm++) {
#pragma unroll
    for (int i = 0; i < 4; i++) {
      const size_t rr = (size_t)(rBase + tm * 16 + i);
#pragma unroll
      for (int tn = 0; tn < 4; tn++)
        Y[rr * 1024 + cBase + tn * 16] = (u16)f2bf(acc[tm][tn][i]);
    }
  }
}

// ---------------- bf16 batched NT GEMM: 128x128, BK=64, XOR-swizzled (measured-good) ----------------
struct Gemm4 { const u16* A[4]; const u16* Bw[4]; u16* Y[4]; };

template <int NG_LOG2>
__global__ __launch_bounds__(256) void gemm_batch(Gemm4 args) {
  const int p = blockIdx.x;
  const int xcd = p & 7;
  const int s = p >> 3;
  const int pr = s >> (3 + NG_LOG2);
  const int cc = s & ((8 << NG_LOG2) - 1);
  const int gate = cc >> 3;
  const int col  = cc & 7;
  const int r = pr * 8 + xcd;

  const u16* __restrict__ A  = args.A[gate];
  const u16* __restrict__ Bw = args.Bw[gate];
  u16* __restrict__ Y = args.Y[gate];

  __shared__ __attribute__((aligned(16))) u16 As[128 * 64];
  __shared__ __attribute__((aligned(16))) u16 Bs[128 * 64];

  const int tid  = threadIdx.x;
  const int lane = tid & 63;
  const int w    = tid >> 6;
  const int wm   = w >> 1;
  const int wn   = w & 1;

  const int rowBlk = r * 128;
  const int colBlk = col * 128;

  const int srow = lane >> 3;
  const int scol = ((lane & 7) ^ srow) * 8;
  const u16* gA[4]; const u16* gB[4]; u16* lA[4]; u16* lB[4];
#pragma unroll
  for (int i = 0; i < 4; i++) {
    const int rr = w * 32 + i * 8;
    gA[i] = A  + (size_t)(rowBlk + rr + srow) * 1024 + scol;
    gB[i] = Bw + (size_t)(colBlk + rr + srow) * 1024 + scol;
    lA[i] = &As[rr * 64];
    lB[i] = &Bs[rr * 64];
  }

  const int swz = (((lane >> 4) ^ (lane & 7)) << 3);
  const int fa = (wm * 64 + (lane & 15)) * 64 + swz;
  const int fb = (wn * 64 + (lane & 15)) * 64 + swz;

  f32x4 acc[4][4] = {};

  for (int k0 = 0; k0 < 1024; k0 += 64) {
#pragma unroll
    for (int i = 0; i < 4; i++) {
      async16(gA[i] + k0, lA[i]);
      async16(gB[i] + k0, lB[i]);
    }
    __syncthreads();
#pragma unroll
    for (int kk = 0; kk < 2; kk++) {
      const int kx = kk << 5;
      bf16x8 af[4], bfr[4];
#pragma unroll
      for (int t = 0; t < 4; t++) {
        af[t]  = *(const bf16x8*)&As[(fa + t * 1024) ^ kx];
        bfr[t] = *(const bf16x8*)&Bs[(fb + t * 1024) ^ kx];
      }
#pragma unroll
      for (int tm = 0; tm < 4; tm++)
#pragma unroll
        for (int tn = 0; tn < 4; tn++)
          acc[tm][tn] = __builtin_amdgcn_mfma_f32_16x16x32_bf16(af[tm], bfr[tn], acc[tm][tn], 0, 0, 0);
    }
    __syncthreads();
  }

  const int rBase = rowBlk + wm * 64 + (lane >> 4) * 4;
  const int cBase = colBlk + wn * 64 + (lane & 15);
#pragma unroll
  for (int tm = 0; tm < 4; tm++) {
#pragma unroll
    for (int i = 0; i < 4; i++) {
      const size_t rr = (size_t)(rBase + tm * 16 + i);
#pragma unroll
      for (int tn = 0; tn < 4; tn++)
        Y[rr * 1024 + cBase + tn * 16] = (u16)f2bf(acc[tm][tn][i]);
    }
  }
}

// ---------------- r gate: wave-per-row, no barriers ----------------
__global__ __launch_bounds__(256) void rgate_kernel(
    const u16* __restrict__ Yrh, const u16* __restrict__ Yrx,
    const u16* __restrict__ hb, const float* __restrict__ gamma,
    const float* __restrict__ beta, u16* __restrict__ hrb) {
  const int row  = blockIdx.x * 4 + (threadIdx.x >> 6);
  const int lane = threadIdx.x & 63;
  const size_t rb = (size_t)row * 1024;

  uint4 qa[2], qb[2], qh[2];
  qa[0] = *(const uint4*)(Yrh + rb + lane * 8);
  qa[1] = *(const uint4*)(Yrh + rb + 512 + lane * 8);
  qb[0] = *(const uint4*)(Yrx + rb + lane * 8);
  qb[1] = *(const uint4*)(Yrx + rb + 512 + lane * 8);
  qh[0] = *(const uint4*)(hb  + rb + lane * 8);
  qh[1] = *(const uint4*)(hb  + rb + 512 + lane * 8);

  float s0 = 0.f, s0q = 0.f, s1 = 0.f, s1q = 0.f;
  float tmp[8];
#pragma unroll
  for (int c = 0; c < 2; c++) {
    unpack8(qa[c], tmp);
#pragma unroll
    for (int j = 0; j < 8; j++) { s0 += tmp[j]; s0q += tmp[j] * tmp[j]; }
    unpack8(qb[c], tmp);
#pragma unroll
    for (int j = 0; j < 8; j++) { s1 += tmp[j]; s1q += tmp[j] * tmp[j]; }
  }
#pragma unroll
  for (int off = 1; off < 64; off <<= 1) {
    s0 += __shfl_xor(s0, off, 64);  s0q += __shfl_xor(s0q, off, 64);
    s1 += __shfl_xor(s1, off, 64);  s1q += __shfl_xor(s1q, off, 64);
  }

  const float inv = 1.0f / 1024.0f;
  const float mu0 = s0 * inv, rs0 = rsqrtf(s0q * inv - mu0 * mu0 + 1e-5f);
  const float mu1 = s1 * inv, rs1 = rsqrtf(s1q * inv - mu1 * mu1 + 1e-5f);

#pragma unroll
  for (int c = 0; c < 2; c++) {
    const int cb = c * 512 + lane * 8;
    float va[8], vb[8], vh[8], o[8];
    unpack8(qa[c], va); unpack8(qb[c], vb); unpack8(qh[c], vh);
#pragma unroll
    for (int j = 0; j < 8; j++) {
      const float ln0 = (va[j] - mu0) * rs0 * gamma[cb + j] + beta[cb + j];
      const float ln1 = (vb[j] - mu1) * rs1 * gamma[1024 + cb + j] + beta[1024 + cb + j];
      const float rg = fast_sigmoid(ln0 + ln1);
      o[j] = vh[j] * rg;
    }
    *(uint4*)(hrb + rb + cb) = pack8(o);  // aliases Yrx: per-thread read-before-write
  }
}

// ---------------- final: wave-per-row, h read in fp32 ----------------
__global__ __launch_bounds__(256) void final_fuse(
    const u16* __restrict__ Yuh, const u16* __restrict__ Yux,
    const u16* __restrict__ Ych, const u16* __restrict__ Ycx,
    const float* __restrict__ h, const float* __restrict__ gamma,
    const float* __restrict__ beta, float* __restrict__ out) {
  const int row  = blockIdx.x * 4 + (threadIdx.x >> 6);
  const int lane = threadIdx.x & 63;
  const size_t rb = (size_t)row * 1024;

  uint4 q0[2], q1[2], q2[2], q3[2];
  float4 hf[4];
#pragma unroll
  for (int c = 0; c < 2; c++) {
    const int cb = c * 512 + lane * 8;
    q0[c] = *(const uint4*)(Yuh + rb + cb);
    q1[c] = *(const uint4*)(Yux + rb + cb);
    q2[c] = *(const uint4*)(Ych + rb + cb);
    q3[c] = *(const uint4*)(Ycx + rb + cb);
    hf[c * 2]     = *(const float4*)(h + rb + cb);
    hf[c * 2 + 1] = *(const float4*)(h + rb + cb + 4);
  }

  float s[8] = {0.f, 0.f, 0.f, 0.f, 0.f, 0.f, 0.f, 0.f};
  float tmp[8];
#pragma unroll
  for (int c = 0; c < 2; c++) {
    unpack8(q0[c], tmp);
#pragma unroll
    for (int j = 0; j < 8; j++) { s[0] += tmp[j]; s[1] += tmp[j] * tmp[j]; }
    unpack8(q1[c], tmp);
#pragma unroll
    for (int j = 0; j < 8; j++) { s[2] += tmp[j]; s[3] += tmp[j] * tmp[j]; }
    unpack8(q2[c], tmp);
#pragma unroll
    for (int j = 0; j < 8; j++) { s[4] += tmp[j]; s[5] += tmp[j] * tmp[j]; }
    unpack8(q3[c], tmp);
#pragma unroll
    for (int j = 0; j < 8; j++) { s[6] += tmp[j]; s[7] += tmp[j] * tmp[j]; }
  }
#pragma unroll
  for (int off = 1; off < 64; off <<= 1) {
#pragma unroll
    for (int q = 0; q < 8; q++) s[q] += __shfl_xor(s[q], off, 64);
  }

  const float inv = 1.0f / 1024.0f;
  const float mu0 = s[0] * inv, rs0 = rsqrtf(s[1] * inv - mu0 * mu0 + 1e-5f);
  const float mu1 = s[2] * inv, rs1 = rsqrtf(s[3] * inv - mu1 * mu1 + 1e-5f);
  const float mu2 = s[4] * inv, rs2 = rsqrtf(s[5] * inv - mu2 * mu2 + 1e-5f);
  const float mu3 = s[6] * inv, rs3 = rsqrtf(s[7] * inv - mu3 * mu3 + 1e-5f);

#pragma unroll
  for (int c = 0; c < 2; c++) {
    const int cb = c * 512 + lane * 8;
    float v0[8], v1[8], v2[8], v3[8];
    unpack8(q0[c], v0); unpack8(q1[c], v1); unpack8(q2[c], v2); unpack8(q3[c], v3);
    const float* hv = (const float*)&hf[c * 2];
    float o[8];
#pragma unroll
    for (int j = 0; j < 8; j++) {
      const int cc = cb + j;
      const float ln2 = (v0[j] - mu0) * rs0 * gamma[2 * 1024 + cc] + beta[2 * 1024 + cc];
      const float ln3 = (v1[j] - mu1) * rs1 * gamma[3 * 1024 + cc] + beta[3 * 1024 + cc];
      const float ln4 = (v2[j] - mu2) * rs2 * gamma[4 * 1024 + cc] + beta[4 * 1024 + cc];
      const float ln5 = (v3[j] - mu3) * rs3 * gamma[5 * 1024 + cc] + beta[5 * 1024 + cc];
      const float u  = fast_sigmoid(ln2 + ln3);
      const float cg = fast_tanh(ln4 + ln5);
      o[j] = (1.0f - u) * hv[j] + u * cg;
    }
    *(float4*)(out + rb + cb)     = *(float4*)&o[0];
    *(float4*)(out + rb + cb + 4) = *(float4*)&o[4];
  }
}

extern "C" void kernel_launch(void* const* d_in, const int* in_sizes, int n_in,
                              void* d_out, int out_size, void* d_ws, size_t ws_size,
                              hipStream_t stream) {
  const float* x  = (const float*)d_in[0];
  const float* h  = (const float*)d_in[1];
  const float* W_r = (const float*)d_in[2];
  const float* U_r = (const float*)d_in[3];
  const float* W_u = (const float*)d_in[4];
  const float* U_u = (const float*)d_in[5];
  const float* W_c = (const float*)d_in[6];
  const float* U_c = (const float*)d_in[7];
  const float* gamma = (const float*)d_in[8];
  const float* beta  = (const float*)d_in[9];
  float* out = (float*)d_out;

  char* ws = (char*)d_ws;
  const size_t MB = 1024 * 1024;
  const size_t SZ_ACT = 16 * MB;     // 8192x1024 bf16

  u16* xb = (u16*)(ws);                       // 16 MiB
  u16* hb = (u16*)(ws + 16 * MB);             // 16 MiB
  u16* wb[4];                                 // bf16 weights: W_u, U_u, W_c, U_c
  for (int i = 0; i < 4; i++) wb[i] = (u16*)(ws + (32 + 2 * i) * MB);
  u8* w8r = (u8*)(ws + 40 * MB);              // W_r fp8 (1 MiB)
  u8* w8u = (u8*)(ws + 41 * MB);              // U_r fp8 (1 MiB)
  char* ybase = ws + 42 * MB;
  u16* Y0 = (u16*)(ybase);                    // r_hidden; reused for c_hidden out
  u16* Y1 = (u16*)(ybase + SZ_ACT);           // r_input;  reused for hr
  u16* Y2 = (u16*)(ybase + 2 * SZ_ACT);       // u_hidden
  u16* Y3 = (u16*)(ybase + 3 * SZ_ACT);       // u_input
  u16* Y5 = (u16*)(ybase + 4 * SZ_ACT);       // c_input (written only in step 4)
  u8* x8 = (u8*)Y5;                           // fp8 x, aliased into Y5 (dead by step 4)
  u8* h8 = (u8*)Y5 + 8 * MB;                  // fp8 h
  // total ws: 42 + 80 = 122 MiB

  // 1) fused convert
  ConvArgs2 ca = {};
  ca.x = x; ca.h = h; ca.wr = W_r; ca.ur = U_r;
  ca.wbf[0] = W_u; ca.wbf[1] = U_u; ca.wbf[2] = W_c; ca.wbf[3] = U_c;
  ca.xb = xb; ca.hb = hb; ca.x8 = x8; ca.h8 = h8; ca.w8r = w8r; ca.w8u = w8u;
  ca.wbo[0] = (u16*)(ws + 32 * MB); ca.wbo[1] = (u16*)(ws + 34 * MB);
  ca.wbo[2] = (u16*)(ws + 36 * MB); ca.wbo[3] = (u16*)(ws + 38 * MB);
  convert_all<<<22528, 256, 0, stream>>>(ca);

  // 2) fp8 MX GEMMs: r_h = h@W_r^T, r_x = x@U_r^T  (1024 blocks)
  GemmF8 gf = {};
  gf.A[0] = h8; gf.Bw[0] = w8r; gf.Y[0] = Y0;
  gf.A[1] = x8; gf.Bw[1] = w8u; gf.Y[1] = Y1;
  gemm_fp8<<<1024, 256, 0, stream>>>(gf);

  // 3) r gate + hr (hr overwrites Y1; per-thread read-before-write)
  rgate_kernel<<<2048, 256, 0, stream>>>(Y0, Y1, hb, gamma, beta, Y1);

  // 4) bf16 batch: u_x, c_x (share xb tile), u_h, c_h  (2048 blocks)
  Gemm4 gb = {};
  gb.A[0] = xb; gb.Bw[0] = wb[1]; gb.Y[0] = Y3;   // u_x = x@U_u^T
  gb.A[1] = xb; gb.Bw[1] = wb[3]; gb.Y[1] = Y5;   // c_x = x@U_c^T
  gb.A[2] = hb; gb.Bw[2] = wb[0]; gb.Y[2] = Y2;   // u_h = h@W_u^T
  gb.A[3] = Y1; gb.Bw[3] = wb[2]; gb.Y[3] = Y0;   // c_h = hr@W_c^T
  gemm_batch<2><<<2048, 256, 0, stream>>>(gb);

  // 5) u, c, out (h in fp32)
  final_fuse<<<2048, 256, 0, stream>>>(Y2, Y3, Y0, Y5, h, gamma, beta, out);
}